// Round 1
// baseline (244.175 us; speedup 1.0000x reference)
//
#include <hip/hip_runtime.h>

#define C_CLS 10
#define G_DIM 8

// Workspace layout (all 4B aligned):
//   float cs[C_CLS*G_DIM]   @ 0      (320 B)
//   int   counts[C_CLS]     @ 320    (40 B)
//   float total             @ 360    (4 B)

__global__ void k_init(float* cs, int* counts, float* total) {
    int t = threadIdx.x;
    if (t < C_CLS * G_DIM) cs[t] = 0.0f;
    if (t < C_CLS) counts[t] = 0;
    if (t == 0) *total = 0.0f;
}

// Pass 1: per-class column sums + counts over masked rows.
__global__ void k_colsum(const float* __restrict__ ga, const int* __restrict__ lbl,
                         float* __restrict__ g_cs, int* __restrict__ g_counts, int N) {
    __shared__ float s_cs[C_CLS * G_DIM];
    __shared__ int s_cnt[C_CLS];
    int t = threadIdx.x;
    if (t < C_CLS * G_DIM) s_cs[t] = 0.0f;
    if (t < C_CLS) s_cnt[t] = 0;
    __syncthreads();

    int stride = gridDim.x * blockDim.x;
    for (int n = blockIdx.x * blockDim.x + t; n < N; n += stride) {
        int l = lbl[n];
        if (l > 0) {
            int c = l - 1;
            const float4* row = (const float4*)(ga + ((size_t)c * N + n) * G_DIM);
            float4 v0 = row[0];
            float4 v1 = row[1];
            atomicAdd(&s_cnt[c], 1);
            float* b = &s_cs[c * G_DIM];
            atomicAdd(&b[0], v0.x);
            atomicAdd(&b[1], v0.y);
            atomicAdd(&b[2], v0.z);
            atomicAdd(&b[3], v0.w);
            atomicAdd(&b[4], v1.x);
            atomicAdd(&b[5], v1.y);
            atomicAdd(&b[6], v1.z);
            atomicAdd(&b[7], v1.w);
        }
    }
    __syncthreads();
    if (t < C_CLS * G_DIM) atomicAdd(&g_cs[t], s_cs[t]);
    if (t < C_CLS) atomicAdd(&g_counts[t], s_cnt[t]);
}

// Pass 2: per-row contribution S*L - D with p_i = a_i/cs, gated by valid[c].
__global__ void k_loss(const float* __restrict__ ga, const int* __restrict__ lbl,
                       const float* __restrict__ g_cs, const int* __restrict__ g_counts,
                       float* __restrict__ g_total, int N) {
    __shared__ float s_inv[C_CLS * G_DIM];
    __shared__ float s_lcs[C_CLS * G_DIM];
    __shared__ float s_val[C_CLS];
    int t = threadIdx.x;
    if (t < C_CLS * G_DIM) {
        float cs = g_cs[t];
        s_inv[t] = 1.0f / cs;
        s_lcs[t] = __logf(cs);
    }
    if (t < C_CLS) s_val[t] = (g_counts[t] >= 2) ? 1.0f : 0.0f;
    __syncthreads();

    float acc = 0.0f;
    int stride = gridDim.x * blockDim.x;
    for (int n = blockIdx.x * blockDim.x + t; n < N; n += stride) {
        int l = lbl[n];
        if (l > 0) {
            int c = l - 1;
            const float4* row = (const float4*)(ga + ((size_t)c * N + n) * G_DIM);
            float4 v0 = row[0];
            float4 v1 = row[1];
            float a[G_DIM] = {v0.x, v0.y, v0.z, v0.w, v1.x, v1.y, v1.z, v1.w};
            const float* inv = &s_inv[c * G_DIM];
            const float* lcs = &s_lcs[c * G_DIM];
            float S = 0.0f, L = 0.0f, D = 0.0f;
#pragma unroll
            for (int g = 0; g < G_DIM; ++g) {
                float s = a[g] * inv[g];
                float lg = __logf(a[g]) - lcs[g];
                S += s;
                L += lg;
                D += s * lg;
            }
            acc += s_val[c] * (S * L - D);
        }
    }

    // wave reduce (64-wide) then block reduce
#pragma unroll
    for (int off = 32; off > 0; off >>= 1) acc += __shfl_down(acc, off, 64);
    __shared__ float s_red[4];  // 256 threads / 64 lanes
    int wid = t >> 6, lid = t & 63;
    if (lid == 0) s_red[wid] = acc;
    __syncthreads();
    if (t == 0) {
        atomicAdd(g_total, s_red[0] + s_red[1] + s_red[2] + s_red[3]);
    }
}

__global__ void k_fin(const int* __restrict__ counts, const float* __restrict__ total,
                      float* __restrict__ out) {
    if (threadIdx.x == 0) {
        int nv = 0;
        for (int c = 0; c < C_CLS; ++c) nv += (counts[c] >= 2) ? 1 : 0;
        out[0] = total[0] / ((float)nv * (float)(G_DIM * (G_DIM - 1)));
    }
}

extern "C" void kernel_launch(void* const* d_in, const int* in_sizes, int n_in,
                              void* d_out, int out_size, void* d_ws, size_t ws_size,
                              hipStream_t stream) {
    const float* ga = (const float*)d_in[0];
    const int* lbl = (const int*)d_in[1];
    float* out = (float*)d_out;
    int N = in_sizes[1];

    char* ws = (char*)d_ws;
    float* cs = (float*)ws;                 // 80 floats
    int* counts = (int*)(ws + 320);         // 10 ints
    float* total = (float*)(ws + 360);      // 1 float

    k_init<<<1, 128, 0, stream>>>(cs, counts, total);
    k_colsum<<<1024, 256, 0, stream>>>(ga, lbl, cs, counts, N);
    k_loss<<<1024, 256, 0, stream>>>(ga, lbl, cs, counts, total, N);
    k_fin<<<1, 64, 0, stream>>>(counts, total, out);
}

// Round 2
// 241.661 us; speedup vs baseline: 1.0104x; 1.0104x over previous
//
#include <hip/hip_runtime.h>

#define C_CLS 10
#define G_DIM 8
#define CHUNKS 128
// per-class accumulator layout in ws: [c][0..7]=cs, [8..15]=R, [16..23]=D, [24]=count
#define ACC_W 26

__global__ void k_init(float* acc) {
    int t = threadIdx.x;
    if (t < C_CLS * ACC_W) acc[t] = 0.0f;
}

__device__ inline float wave_red(float v) {
#pragma unroll
    for (int off = 32; off > 0; off >>= 1) v += __shfl_down(v, off, 64);
    return v;
}

// One dense pass. Block (cx, c): stream rows [base, end) of plane c + labels,
// accumulate masked sums cs_i, R_i = sum a_i*L, D_i = sum a_i*la_i, count.
__global__ void __launch_bounds__(256) k_main(const float* __restrict__ ga,
                                              const int* __restrict__ lbl,
                                              float* __restrict__ g_acc, int N) {
    const int c = blockIdx.y;
    const int chunk_len = (N + CHUNKS - 1) / CHUNKS;
    const int base = blockIdx.x * chunk_len;
    const int end = min(base + chunk_len, N);

    float cs_a[G_DIM], R_a[G_DIM], D_a[G_DIM];
#pragma unroll
    for (int g = 0; g < G_DIM; ++g) { cs_a[g] = 0.0f; R_a[g] = 0.0f; D_a[g] = 0.0f; }
    float cnt = 0.0f;

    const float* plane = ga + (size_t)c * N * G_DIM;
    for (int n = base + (int)threadIdx.x; n < end; n += blockDim.x) {
        const float4* row = (const float4*)(plane + (size_t)n * G_DIM);
        float4 v0 = row[0];
        float4 v1 = row[1];
        int l = lbl[n];
        float m = (l == c + 1) ? 1.0f : 0.0f;
        float a[G_DIM] = {v0.x, v0.y, v0.z, v0.w, v1.x, v1.y, v1.z, v1.w};
        float la[G_DIM];
        float L = 0.0f;
#pragma unroll
        for (int g = 0; g < G_DIM; ++g) {
            la[g] = __logf(fmaxf(a[g], 1e-30f));  // clamp: avoid 0*(-inf)=NaN on unmasked rows
            L += la[g];
        }
        cnt += m;
#pragma unroll
        for (int g = 0; g < G_DIM; ++g) {
            float am = a[g] * m;
            cs_a[g] += am;
            R_a[g] = fmaf(am, L, R_a[g]);
            D_a[g] = fmaf(am, la[g], D_a[g]);
        }
    }

    // wave reduce all 25 accumulators
#pragma unroll
    for (int g = 0; g < G_DIM; ++g) {
        cs_a[g] = wave_red(cs_a[g]);
        R_a[g] = wave_red(R_a[g]);
        D_a[g] = wave_red(D_a[g]);
    }
    cnt = wave_red(cnt);

    __shared__ float s_part[4][ACC_W];  // 4 waves x 25 used
    int wid = threadIdx.x >> 6, lid = threadIdx.x & 63;
    if (lid == 0) {
#pragma unroll
        for (int g = 0; g < G_DIM; ++g) {
            s_part[wid][g] = cs_a[g];
            s_part[wid][8 + g] = R_a[g];
            s_part[wid][16 + g] = D_a[g];
        }
        s_part[wid][24] = cnt;
    }
    __syncthreads();
    int t = threadIdx.x;
    if (t < ACC_W - 1) {
        float v = s_part[0][t] + s_part[1][t] + s_part[2][t] + s_part[3][t];
        atomicAdd(&g_acc[c * ACC_W + t], v);
    }
}

__global__ void k_fin(const float* __restrict__ acc, float* __restrict__ out) {
    if (threadIdx.x == 0) {
        float tot = 0.0f;
        int nv = 0;
        for (int c = 0; c < C_CLS; ++c) {
            const float* a = acc + c * ACC_W;
            float cnt = a[24];
            if (cnt >= 2.0f) {
                nv++;
                float Lc = 0.0f, s = 0.0f;
                for (int i = 0; i < G_DIM; ++i) {
                    float cs = a[i];
                    Lc += __logf(cs);
                    s += (a[8 + i] - a[16 + i]) / cs;
                }
                tot += s - (float)(G_DIM - 1) * Lc;
            }
        }
        out[0] = tot / ((float)nv * (float)(G_DIM * (G_DIM - 1)));
    }
}

extern "C" void kernel_launch(void* const* d_in, const int* in_sizes, int n_in,
                              void* d_out, int out_size, void* d_ws, size_t ws_size,
                              hipStream_t stream) {
    const float* ga = (const float*)d_in[0];
    const int* lbl = (const int*)d_in[1];
    float* out = (float*)d_out;
    int N = in_sizes[1];

    float* acc = (float*)d_ws;  // C_CLS * ACC_W floats

    k_init<<<1, 512, 0, stream>>>(acc);
    dim3 grid(CHUNKS, C_CLS);
    k_main<<<grid, 256, 0, stream>>>(ga, lbl, acc, N);
    k_fin<<<1, 64, 0, stream>>>(acc, out);
}

// Round 3
// 224.724 us; speedup vs baseline: 1.0866x; 1.0754x over previous
//
#include <hip/hip_runtime.h>

#define C_CLS 10
#define G_DIM 8
#define CHUNKS 128
#define ACC_W 25  // [0..7]=cs, [8..15]=R, [16..23]=D, [24]=count

__device__ inline float wave_red(float v) {
#pragma unroll
    for (int off = 32; off > 0; off >>= 1) v += __shfl_down(v, off, 64);
    return v;
}

// One sparse-predicated pass. Block (cx, c): walk rows [base,end) of plane c,
// load the 32B row ONLY when label matches (line-level fetch ~32% of dense).
// Accumulate cs_i, R_i = sum a_i*L, D_i = sum a_i*la_i, count.
__global__ void __launch_bounds__(256) k_main(const float* __restrict__ ga,
                                              const int* __restrict__ lbl,
                                              float* __restrict__ part, int N) {
    const int c = blockIdx.y;
    const int chunk_len = (N + CHUNKS - 1) / CHUNKS;
    const int base = blockIdx.x * chunk_len;
    const int end = min(base + chunk_len, N);

    float cs_a[G_DIM] = {0,0,0,0,0,0,0,0};
    float R_a[G_DIM]  = {0,0,0,0,0,0,0,0};
    float D_a[G_DIM]  = {0,0,0,0,0,0,0,0};
    float cnt = 0.0f;

    const float* plane = ga + (size_t)c * N * G_DIM;
    for (int n = base + (int)threadIdx.x; n < end; n += blockDim.x) {
        if (lbl[n] == c + 1) {
            const float4* row = (const float4*)(plane + (size_t)n * G_DIM);
            float4 v0 = row[0];
            float4 v1 = row[1];
            float a[G_DIM] = {v0.x, v0.y, v0.z, v0.w, v1.x, v1.y, v1.z, v1.w};
            float la[G_DIM];
            float L = 0.0f;
#pragma unroll
            for (int g = 0; g < G_DIM; ++g) {
                la[g] = __logf(fmaxf(a[g], 1e-30f));
                L += la[g];
            }
            cnt += 1.0f;
#pragma unroll
            for (int g = 0; g < G_DIM; ++g) {
                cs_a[g] += a[g];
                R_a[g] = fmaf(a[g], L, R_a[g]);
                D_a[g] = fmaf(a[g], la[g], D_a[g]);
            }
        }
    }

    // wave reduce 25 accumulators, then block reduce via LDS
#pragma unroll
    for (int g = 0; g < G_DIM; ++g) {
        cs_a[g] = wave_red(cs_a[g]);
        R_a[g]  = wave_red(R_a[g]);
        D_a[g]  = wave_red(D_a[g]);
    }
    cnt = wave_red(cnt);

    __shared__ float s_part[4][ACC_W];
    int wid = threadIdx.x >> 6, lid = threadIdx.x & 63;
    if (lid == 0) {
#pragma unroll
        for (int g = 0; g < G_DIM; ++g) {
            s_part[wid][g]      = cs_a[g];
            s_part[wid][8 + g]  = R_a[g];
            s_part[wid][16 + g] = D_a[g];
        }
        s_part[wid][24] = cnt;
    }
    __syncthreads();
    int t = threadIdx.x;
    if (t < ACC_W) {
        float v = s_part[0][t] + s_part[1][t] + s_part[2][t] + s_part[3][t];
        // per-block private slot: no atomics, no zero-init kernel needed
        part[((size_t)c * CHUNKS + blockIdx.x) * ACC_W + t] = v;
    }
}

__global__ void k_fin(const float* __restrict__ part, float* __restrict__ out) {
    __shared__ float s_acc[C_CLS][ACC_W];
    int t = threadIdx.x;
    if (t < C_CLS * ACC_W) {
        int c = t / ACC_W, j = t % ACC_W;
        float s = 0.0f;
        for (int ch = 0; ch < CHUNKS; ++ch)
            s += part[((size_t)c * CHUNKS + ch) * ACC_W + j];
        s_acc[c][j] = s;
    }
    __syncthreads();
    if (t == 0) {
        float tot = 0.0f;
        int nv = 0;
        for (int c = 0; c < C_CLS; ++c) {
            if (s_acc[c][24] >= 2.0f) {
                nv++;
                float K = 0.0f, s = 0.0f;
                for (int i = 0; i < G_DIM; ++i) {
                    float cs = s_acc[c][i];
                    K += __logf(cs);
                    s += (s_acc[c][8 + i] - s_acc[c][16 + i]) / cs;
                }
                tot += s - (float)(G_DIM - 1) * K;
            }
        }
        out[0] = tot / ((float)nv * (float)(G_DIM * (G_DIM - 1)));
    }
}

extern "C" void kernel_launch(void* const* d_in, const int* in_sizes, int n_in,
                              void* d_out, int out_size, void* d_ws, size_t ws_size,
                              hipStream_t stream) {
    const float* ga = (const float*)d_in[0];
    const int* lbl = (const int*)d_in[1];
    float* out = (float*)d_out;
    int N = in_sizes[1];

    float* part = (float*)d_ws;  // C_CLS * CHUNKS * ACC_W floats = 128 KB

    dim3 grid(CHUNKS, C_CLS);
    k_main<<<grid, 256, 0, stream>>>(ga, lbl, part, N);
    k_fin<<<1, 256, 0, stream>>>(part, out);
}